// Round 1
// baseline (1723.830 us; speedup 1.0000x reference)
//
#include <hip/hip_runtime.h>
#include <hip/hip_bf16.h>

// Problem: B=16, C=64, H=256, W=256, P=2
// x: (B,C,H,W) f32; v: (P,1,1,H,W) f32; conv_w: (P,64,64) f32; tau: (P,1,1,H,W) f32
// y = haar2d_inv( sum_p softthr( (haar2d(x)*v_p) @ w_p^T, tau_p ) ) + x
//
// Pipeline (ws = one 256 MiB f32 buffer in (b, c, w_ref, h) transposed layout):
//   k_fwdW : x -> Hw(x), transposed+subband-permuted store to ws
//   k_mid  : per (b,w) slab: Hh fwd -> channel mix/threshold -> Hh inv, in-place in ws
//   k_invW : ws -> Hw^{-1} + x -> y (natural layout)

namespace {

constexpr float kNorm = 0.70710678118654752440f;

// in-place lifting position -> reference subband position (n=256, 8 levels)
__device__ __forceinline__ int ip2ref(int p) {
  if (p == 0) return 0;
  const int j = __builtin_ctz(p) + 1;
  return (256 >> j) + (p >> j);
}
// reference subband position -> in-place lifting position
__device__ __forceinline__ int ref2ip(int r) {
  if (r == 0) return 0;
  const int tb = 31 - __builtin_clz(r);  // floor(log2(r))
  const int j = 8 - tb;
  return ((r - (1 << tb)) << j) | (1 << (j - 1));
}

// ---------------- Kernel 1: forward Haar along W, transposed store ----------
__global__ __launch_bounds__(256) void k_fwdW(const float* __restrict__ x,
                                              float* __restrict__ xt) {
  __shared__ float tile[32][257];  // 32 rows (h) x 256 cols (w), pitch 257
  const int blk = blockIdx.x;      // img*8 + htile
  const int img = blk >> 3;        // b*64 + c
  const int h0 = (blk & 7) << 5;
  const int tid = threadIdx.x;

  const float* __restrict__ src = x + ((size_t)img << 16) + ((size_t)h0 << 8);
#pragma unroll
  for (int j = 0; j < 32; ++j) tile[j][tid] = src[(j << 8) + tid];
  __syncthreads();

  // in-place lifting forward along w (1 sync per level, no pair overlap)
#pragma unroll
  for (int ls = 1; ls <= 8; ++ls) {
    const int s = 1 << ls;
    const int hs = s >> 1;
    const int ppr = 256 >> ls;  // pairs per row
    const int total = 32 * ppr;
    for (int idx = tid; idx < total; idx += 256) {
      const int r = idx / ppr;
      const int i = idx - r * ppr;
      float* row = &tile[r][0];
      const int p0 = i * s;
      const float e = row[p0];
      const float o = row[p0 + hs];
      row[p0] = kNorm * (e + o);
      row[p0 + hs] = kNorm * (e - o);
    }
    __syncthreads();
  }

  // transposed write with in-place -> subband permutation: xt[img][wref][h]
  const int g8 = tid >> 5;
  const int l = tid & 31;
  float* __restrict__ dst = xt + ((size_t)img << 16) + h0;
#pragma unroll
  for (int k = 0; k < 32; ++k) {
    const int wp = g8 + (k << 3);
    const int wr = ip2ref(wp);
    dst[((size_t)wr << 8) + l] = tile[l][wp];  // 32 consecutive h per wr: coalesced
  }
}

// ---------------- Kernel 2: Hh fwd + channel mix + Hh inv (in-place) --------
__global__ __launch_bounds__(256) void k_mid(float* __restrict__ ws,
                                             const float* __restrict__ vv,
                                             const float* __restrict__ cw,
                                             const float* __restrict__ tt) {
  __shared__ float tile[64][256];  // 64 channels x 256 h (exactly 64 KiB)
  const int blk = blockIdx.x;      // b*256 + w
  const int b = blk >> 8;
  const int w = blk & 255;
  const int tid = threadIdx.x;

  float* __restrict__ base = ws + ((size_t)b << 22) + ((size_t)w << 8);
  // load slab: row per channel, contiguous 1 KiB each -> coalesced
#pragma unroll
  for (int c = 0; c < 64; ++c) tile[c][tid] = base[((size_t)c << 16) + tid];

  // per-thread pixel metadata (thread tid owns in-place h position = tid)
  const int hr = ip2ref(tid);
  const float v0 = vv[(hr << 8) + w];
  const float v1 = vv[65536 + (hr << 8) + w];
  const float tau0 = tt[(hr << 8) + w];
  const float tau1 = tt[65536 + (hr << 8) + w];
  __syncthreads();

  // forward Haar along h for each channel row (in-place lifting)
#pragma unroll
  for (int ls = 1; ls <= 8; ++ls) {
    const int s = 1 << ls;
    const int hs = s >> 1;
    const int ppr = 256 >> ls;
    const int total = 64 * ppr;
    for (int idx = tid; idx < total; idx += 256) {
      const int c = idx / ppr;
      const int i = idx - c * ppr;
      float* row = &tile[c][0];
      const int p0 = i * s;
      const float e = row[p0];
      const float o = row[p0 + hs];
      row[p0] = kNorm * (e + o);
      row[p0 + hs] = kNorm * (e - o);
    }
    __syncthreads();
  }

  // pull this thread's channel vector into registers (stride-1 across lanes)
  float f[64];
#pragma unroll
  for (int c = 0; c < 64; ++c) f[c] = tile[c][tid];
  __syncthreads();  // all reads done before mix writes

  // channel mix: acc_o = sum_p softthr(v_p * <f, w_p[o,:]>, tau_p)
  for (int o = 0; o < 64; ++o) {
    const float* __restrict__ w0 = cw + (o << 6);           // uniform -> s_load
    const float* __restrict__ w1 = cw + 4096 + (o << 6);
    float a0 = 0.f, a1 = 0.f, a2 = 0.f, a3 = 0.f;
    float b0 = 0.f, b1 = 0.f, b2 = 0.f, b3 = 0.f;
#pragma unroll
    for (int c = 0; c < 64; c += 4) {
      a0 = fmaf(f[c + 0], w0[c + 0], a0);
      a1 = fmaf(f[c + 1], w0[c + 1], a1);
      a2 = fmaf(f[c + 2], w0[c + 2], a2);
      a3 = fmaf(f[c + 3], w0[c + 3], a3);
      b0 = fmaf(f[c + 0], w1[c + 0], b0);
      b1 = fmaf(f[c + 1], w1[c + 1], b1);
      b2 = fmaf(f[c + 2], w1[c + 2], b2);
      b3 = fmaf(f[c + 3], w1[c + 3], b3);
    }
    const float g0 = ((a0 + a1) + (a2 + a3)) * v0;
    const float g1 = ((b0 + b1) + (b2 + b3)) * v1;
    float r = 0.f;
    const float p0 = fabsf(g0) - tau0;
    if (p0 > 0.f) r += copysignf(p0, g0);
    const float p1 = fabsf(g1) - tau1;
    if (p1 > 0.f) r += copysignf(p1, g1);
    tile[o][tid] = r;
  }
  __syncthreads();

  // inverse Haar along h (in-place lifting, reverse level order)
#pragma unroll
  for (int ls = 8; ls >= 1; --ls) {
    const int s = 1 << ls;
    const int hs = s >> 1;
    const int ppr = 256 >> ls;
    const int total = 64 * ppr;
    for (int idx = tid; idx < total; idx += 256) {
      const int c = idx / ppr;
      const int i = idx - c * ppr;
      float* row = &tile[c][0];
      const int p0 = i * s;
      const float a = row[p0];
      const float d = row[p0 + hs];
      row[p0] = kNorm * (a + d);
      row[p0 + hs] = kNorm * (a - d);
    }
    __syncthreads();
  }

  // in-place store back (block footprint is private: safe)
#pragma unroll
  for (int o = 0; o < 64; ++o) base[((size_t)o << 16) + tid] = tile[o][tid];
}

// ---------------- Kernel 3: inverse Haar along W + residual add -------------
__global__ __launch_bounds__(256) void k_invW(const float* __restrict__ at,
                                              const float* __restrict__ x,
                                              float* __restrict__ y) {
  __shared__ float tile[256][33];  // 256 w (in-place order) x 32 h, pitch 33
  const int blk = blockIdx.x;      // img*8 + htile
  const int img = blk >> 3;
  const int h0 = (blk & 7) << 5;
  const int tid = threadIdx.x;
  const int g8 = tid >> 5;
  const int l = tid & 31;

  // gather: subband position -> in-place position (coalesced 128 B per wr row)
  const float* __restrict__ base = at + ((size_t)img << 16) + h0;
#pragma unroll
  for (int k = 0; k < 32; ++k) {
    const int wr = (g8 << 5) + k;
    const int wp = ref2ip(wr);
    tile[wp][l] = base[((size_t)wr << 8) + l];
  }
  __syncthreads();

  // inverse lifting along w (first index), per h column
#pragma unroll
  for (int ls = 8; ls >= 1; --ls) {
    const int s = 1 << ls;
    const int hs = s >> 1;
    const int ppc = 256 >> ls;  // pairs per column
    const int total = 32 * ppc;
    for (int idx = tid; idx < total; idx += 256) {
      const int hc = idx & 31;
      const int i = idx >> 5;
      const int p0 = i * s;
      const float a = tile[p0][hc];
      const float d = tile[p0 + hs][hc];
      tile[p0][hc] = kNorm * (a + d);
      tile[p0 + hs][hc] = kNorm * (a - d);
    }
    __syncthreads();
  }

  // y = tile + x, natural layout, coalesced
  const float* __restrict__ xs = x + ((size_t)img << 16) + ((size_t)h0 << 8);
  float* __restrict__ yd = y + ((size_t)img << 16) + ((size_t)h0 << 8);
#pragma unroll
  for (int j = 0; j < 32; ++j) {
    yd[(j << 8) + tid] = tile[tid][j] + xs[(j << 8) + tid];
  }
}

}  // namespace

extern "C" void kernel_launch(void* const* d_in, const int* in_sizes, int n_in,
                              void* d_out, int out_size, void* d_ws, size_t ws_size,
                              hipStream_t stream) {
  (void)in_sizes; (void)n_in; (void)out_size; (void)ws_size;
  const float* x  = (const float*)d_in[0];
  const float* vv = (const float*)d_in[1];
  const float* cw = (const float*)d_in[2];
  const float* tt = (const float*)d_in[3];
  float* y  = (float*)d_out;
  float* ws = (float*)d_ws;  // needs 256 MiB

  k_fwdW<<<8192, 256, 0, stream>>>(x, ws);
  k_mid <<<4096, 256, 0, stream>>>(ws, vv, cw, tt);
  k_invW<<<8192, 256, 0, stream>>>(ws, x, y);
}

// Round 2
// 765.818 us; speedup vs baseline: 2.2510x; 2.2510x over previous
//
#include <hip/hip_runtime.h>
#include <hip/hip_bf16.h>

// Problem: B=16, C=64, H=256, W=256, P=2
// x: (B,C,H,W) f32; v: (P,1,1,H,W) f32; conv_w: (P,64,64) f32; tau: (P,1,1,H,W) f32
// y = haar2d_inv( sum_p softthr( (haar2d(x)*v_p) @ w_p^T, tau_p ) ) + x
//
// Pipeline (ws = one 256 MiB f32 buffer in (b, c, w_ref, h) transposed layout):
//   k_fwdW : x -> Hw(x), transposed+subband-permuted store to ws
//   k_mid  : per (b,w) slab: Hh fwd -> channel mix/threshold -> Hh inv, in-place in ws
//   k_invW : ws -> Hw^{-1} + x -> y (natural layout)

namespace {

constexpr float kNorm = 0.70710678118654752440f;

// in-place lifting position -> reference subband position (n=256, 8 levels)
__device__ __forceinline__ int ip2ref(int p) {
  if (p == 0) return 0;
  const int j = __builtin_ctz(p) + 1;
  return (256 >> j) + (p >> j);
}
// reference subband position -> in-place lifting position
__device__ __forceinline__ int ref2ip(int r) {
  if (r == 0) return 0;
  const int tb = 31 - __builtin_clz(r);  // floor(log2(r))
  const int j = 8 - tb;
  return ((r - (1 << tb)) << j) | (1 << (j - 1));
}

// ---------------- Kernel 1: forward Haar along W, transposed store ----------
__global__ __launch_bounds__(256) void k_fwdW(const float* __restrict__ x,
                                              float* __restrict__ xt) {
  __shared__ float tile[32][257];  // 32 rows (h) x 256 cols (w), pitch 257
  const int blk = blockIdx.x;      // img*8 + htile
  const int img = blk >> 3;        // b*64 + c
  const int h0 = (blk & 7) << 5;
  const int tid = threadIdx.x;

  const float* __restrict__ src = x + ((size_t)img << 16) + ((size_t)h0 << 8);
#pragma unroll
  for (int j = 0; j < 32; ++j) tile[j][tid] = src[(j << 8) + tid];
  __syncthreads();

  // in-place lifting forward along w (1 sync per level, no pair overlap)
#pragma unroll
  for (int ls = 1; ls <= 8; ++ls) {
    const int s = 1 << ls;
    const int hs = s >> 1;
    const int ppr = 256 >> ls;  // pairs per row
    const int total = 32 * ppr;
    for (int idx = tid; idx < total; idx += 256) {
      const int r = idx / ppr;
      const int i = idx - r * ppr;
      float* row = &tile[r][0];
      const int p0 = i * s;
      const float e = row[p0];
      const float o = row[p0 + hs];
      row[p0] = kNorm * (e + o);
      row[p0 + hs] = kNorm * (e - o);
    }
    __syncthreads();
  }

  // transposed write with in-place -> subband permutation: xt[img][wref][h]
  const int g8 = tid >> 5;
  const int l = tid & 31;
  float* __restrict__ dst = xt + ((size_t)img << 16) + h0;
#pragma unroll
  for (int k = 0; k < 32; ++k) {
    const int wp = g8 + (k << 3);
    const int wr = ip2ref(wp);
    dst[((size_t)wr << 8) + l] = tile[l][wp];  // 32 consecutive h per wr: coalesced
  }
}

// ---------------- Kernel 2: Hh fwd + channel mix + Hh inv (in-place) --------
// LDS layout: rotation swizzle addr(c,h) = c*256 + ((h+c)&255).
// With c-fastest lane mapping every LDS access below is <=2-way (free).
__device__ __forceinline__ int swz(int c, int h) {
  return (c << 8) | ((h + c) & 255);
}

__global__ __launch_bounds__(256, 2) void k_mid(float* __restrict__ ws,
                                                const float* __restrict__ vv,
                                                const float* __restrict__ cw,
                                                const float* __restrict__ tt) {
  __shared__ float tile[16384];  // 64 KiB: 64 channels x 256 h, swizzled
  const int blk = blockIdx.x;    // b*256 + w
  const int b = blk >> 8;
  const int w = blk & 255;
  const int tid = threadIdx.x;
  const int lane = tid & 63;
  const int wv = tid >> 6;

  float* __restrict__ base = ws + ((size_t)b << 22) + ((size_t)w << 8);

  // ---- slab load: rows of 256 floats, float4 global, conflict-free LDS ----
  // g = (k<<2)|wv selects a 4-row group; lane = (q<<2)|r -> row c0+r, chunk q.
  const int lr = lane & 3;
  const int lq = lane >> 2;  // 0..15
#pragma unroll
  for (int k = 0; k < 4; ++k) {
    const int c = (k << 4) | (wv << 2) | lr;
#pragma unroll
    for (int j = 0; j < 4; ++j) {
      const int h0 = ((lq + (j << 4)) << 2);
      const float4 d = *reinterpret_cast<const float4*>(
          base + ((size_t)c << 16) + h0);
      tile[swz(c, h0 + 0)] = d.x;
      tile[swz(c, h0 + 1)] = d.y;
      tile[swz(c, h0 + 2)] = d.z;
      tile[swz(c, h0 + 3)] = d.w;
    }
  }

  // per-thread pixel metadata (thread tid owns in-place h position = tid)
  const int hr = ip2ref(tid);
  const float v0 = vv[(hr << 8) + w];
  const float v1 = vv[65536 + (hr << 8) + w];
  const float tau0 = tt[(hr << 8) + w];
  const float tau1 = tt[65536 + (hr << 8) + w];
  __syncthreads();

  // ---- forward Haar along h: two levels per barrier (quad lifting) ----
#pragma unroll
  for (int ls = 1; ls <= 7; ls += 2) {
    const int s = 1 << ls;
    const int hs = s >> 1;
    const int s2 = s << 1;
    const int total = (128 >> ls) << 6;  // quads_per_row * 64 channels
    for (int idx = tid; idx < total; idx += 256) {
      const int c = idx & 63;
      const int q = idx >> 6;
      const int p0 = q * s2;
      const float e0 = tile[swz(c, p0)];
      const float o0 = tile[swz(c, p0 + hs)];
      const float e1 = tile[swz(c, p0 + s)];
      const float o1 = tile[swz(c, p0 + s + hs)];
      const float a0 = kNorm * (e0 + o0);
      const float d0 = kNorm * (e0 - o0);
      const float a1 = kNorm * (e1 + o1);
      const float d1 = kNorm * (e1 - o1);
      tile[swz(c, p0)]          = kNorm * (a0 + a1);
      tile[swz(c, p0 + s)]      = kNorm * (a0 - a1);
      tile[swz(c, p0 + hs)]     = d0;
      tile[swz(c, p0 + s + hs)] = d1;
    }
    __syncthreads();
  }

  // ---- pull this thread's channel vector into registers ----
  float f[64];
#pragma unroll
  for (int c = 0; c < 64; ++c) f[c] = tile[swz(c, tid)];
  __syncthreads();  // all reads done before mix writes

  // ---- channel mix: acc_o = sum_p softthr(v_p * <f, w_p[o,:]>, tau_p) ----
  for (int o = 0; o < 64; o += 2) {
    const float* __restrict__ wa0 = cw + (o << 6);  // uniform -> s_load
    const float* __restrict__ wa1 = wa0 + 64;
    const float* __restrict__ wb0 = cw + 4096 + (o << 6);
    const float* __restrict__ wb1 = wb0 + 64;
    float a00 = 0.f, a01 = 0.f, a10 = 0.f, a11 = 0.f;
    float b00 = 0.f, b01 = 0.f, b10 = 0.f, b11 = 0.f;
#pragma unroll
    for (int c = 0; c < 64; c += 2) {
      a00 = fmaf(f[c + 0], wa0[c + 0], a00);
      a01 = fmaf(f[c + 1], wa0[c + 1], a01);
      a10 = fmaf(f[c + 0], wa1[c + 0], a10);
      a11 = fmaf(f[c + 1], wa1[c + 1], a11);
      b00 = fmaf(f[c + 0], wb0[c + 0], b00);
      b01 = fmaf(f[c + 1], wb0[c + 1], b01);
      b10 = fmaf(f[c + 0], wb1[c + 0], b10);
      b11 = fmaf(f[c + 1], wb1[c + 1], b11);
    }
    const float g0 = (a00 + a01) * v0;
    const float g1 = (a10 + a11) * v0;
    const float h0v = (b00 + b01) * v1;
    const float h1v = (b10 + b11) * v1;
    float r0 = 0.f, r1 = 0.f;
    const float p00 = fabsf(g0) - tau0;
    if (p00 > 0.f) r0 += copysignf(p00, g0);
    const float p01 = fabsf(h0v) - tau1;
    if (p01 > 0.f) r0 += copysignf(p01, h0v);
    const float p10 = fabsf(g1) - tau0;
    if (p10 > 0.f) r1 += copysignf(p10, g1);
    const float p11 = fabsf(h1v) - tau1;
    if (p11 > 0.f) r1 += copysignf(p11, h1v);
    tile[swz(o, tid)] = r0;
    tile[swz(o + 1, tid)] = r1;
  }
  __syncthreads();

  // ---- inverse Haar along h: two levels per barrier (quad lifting) ----
#pragma unroll
  for (int ls = 8; ls >= 2; ls -= 2) {
    const int s = 1 << ls;
    const int hs = s >> 1;
    const int hq = hs >> 1;
    const int total = (256 >> ls) << 6;  // quads_per_row * 64 channels
    for (int idx = tid; idx < total; idx += 256) {
      const int c = idx & 63;
      const int q = idx >> 6;
      const int p0 = q * s;
      const float a = tile[swz(c, p0)];
      const float d = tile[swz(c, p0 + hs)];
      const float u0 = kNorm * (a + d);   // level-ls inverse
      const float u1 = kNorm * (a - d);
      const float d0 = tile[swz(c, p0 + hq)];
      const float d1 = tile[swz(c, p0 + hs + hq)];
      tile[swz(c, p0)]           = kNorm * (u0 + d0);  // level-(ls-1) inverse
      tile[swz(c, p0 + hq)]      = kNorm * (u0 - d0);
      tile[swz(c, p0 + hs)]      = kNorm * (u1 + d1);
      tile[swz(c, p0 + hs + hq)] = kNorm * (u1 - d1);
    }
    __syncthreads();
  }

  // ---- store back (mirror of slab load; block footprint private) ----
#pragma unroll
  for (int k = 0; k < 4; ++k) {
    const int c = (k << 4) | (wv << 2) | lr;
#pragma unroll
    for (int j = 0; j < 4; ++j) {
      const int h0 = ((lq + (j << 4)) << 2);
      float4 d;
      d.x = tile[swz(c, h0 + 0)];
      d.y = tile[swz(c, h0 + 1)];
      d.z = tile[swz(c, h0 + 2)];
      d.w = tile[swz(c, h0 + 3)];
      *reinterpret_cast<float4*>(base + ((size_t)c << 16) + h0) = d;
    }
  }
}

// ---------------- Kernel 3: inverse Haar along W + residual add -------------
__global__ __launch_bounds__(256) void k_invW(const float* __restrict__ at,
                                              const float* __restrict__ x,
                                              float* __restrict__ y) {
  __shared__ float tile[256][33];  // 256 w (in-place order) x 32 h, pitch 33
  const int blk = blockIdx.x;      // img*8 + htile
  const int img = blk >> 3;
  const int h0 = (blk & 7) << 5;
  const int tid = threadIdx.x;
  const int g8 = tid >> 5;
  const int l = tid & 31;

  // gather: subband position -> in-place position (coalesced 128 B per wr row)
  const float* __restrict__ base = at + ((size_t)img << 16) + h0;
#pragma unroll
  for (int k = 0; k < 32; ++k) {
    const int wr = (g8 << 5) + k;
    const int wp = ref2ip(wr);
    tile[wp][l] = base[((size_t)wr << 8) + l];
  }
  __syncthreads();

  // inverse lifting along w (first index), per h column
#pragma unroll
  for (int ls = 8; ls >= 1; --ls) {
    const int s = 1 << ls;
    const int hs = s >> 1;
    const int ppc = 256 >> ls;  // pairs per column
    const int total = 32 * ppc;
    for (int idx = tid; idx < total; idx += 256) {
      const int hc = idx & 31;
      const int i = idx >> 5;
      const int p0 = i * s;
      const float a = tile[p0][hc];
      const float d = tile[p0 + hs][hc];
      tile[p0][hc] = kNorm * (a + d);
      tile[p0 + hs][hc] = kNorm * (a - d);
    }
    __syncthreads();
  }

  // y = tile + x, natural layout, coalesced
  const float* __restrict__ xs = x + ((size_t)img << 16) + ((size_t)h0 << 8);
  float* __restrict__ yd = y + ((size_t)img << 16) + ((size_t)h0 << 8);
#pragma unroll
  for (int j = 0; j < 32; ++j) {
    yd[(j << 8) + tid] = tile[tid][j] + xs[(j << 8) + tid];
  }
}

}  // namespace

extern "C" void kernel_launch(void* const* d_in, const int* in_sizes, int n_in,
                              void* d_out, int out_size, void* d_ws, size_t ws_size,
                              hipStream_t stream) {
  (void)in_sizes; (void)n_in; (void)out_size; (void)ws_size;
  const float* x  = (const float*)d_in[0];
  const float* vv = (const float*)d_in[1];
  const float* cw = (const float*)d_in[2];
  const float* tt = (const float*)d_in[3];
  float* y  = (float*)d_out;
  float* ws = (float*)d_ws;  // needs 256 MiB

  k_fwdW<<<8192, 256, 0, stream>>>(x, ws);
  k_mid <<<4096, 256, 0, stream>>>(ws, vv, cw, tt);
  k_invW<<<8192, 256, 0, stream>>>(ws, x, y);
}

// Round 3
// 393.432 us; speedup vs baseline: 4.3815x; 1.9465x over previous
//
#include <hip/hip_runtime.h>
#include <hip/hip_bf16.h>

// Problem: B=16, C=64, H=256, W=256, P=2
// y = haar2d_inv( sum_p softthr( (haar2d(x)*v_p) @ w_p^T, tau_p ) ) + x
//
// Pipeline (ws = bf16 buffer in (b, c, w_ref, h) transposed layout, 128 MiB):
//   k_fwdW : x(f32) -> Hw(x), transposed+subband-permuted bf16 store to ws
//   k_mid  : per (b,w) slab: Hh fwd (f32 LDS) -> MFMA channel mix (bf16 in,
//            f32 acc, v/tau applied post-GEMM) -> Hh inv -> bf16 store in place
//   k_invW : ws -> Hw^{-1} + x -> y (f32, natural layout)

namespace {

constexpr float kNorm = 0.70710678118654752440f;

typedef __attribute__((ext_vector_type(8))) short short8;
typedef __attribute__((ext_vector_type(4))) float f32x4;
typedef __attribute__((ext_vector_type(8))) unsigned short ushort8;

// in-place lifting position -> reference subband position (n=256, 8 levels)
__device__ __forceinline__ int ip2ref(int p) {
  if (p == 0) return 0;
  const int j = __builtin_ctz(p) + 1;
  return (256 >> j) + (p >> j);
}
// reference subband position -> in-place lifting position
__device__ __forceinline__ int ref2ip(int r) {
  if (r == 0) return 0;
  const int tb = 31 - __builtin_clz(r);
  const int j = 8 - tb;
  return ((r - (1 << tb)) << j) | (1 << (j - 1));
}

__device__ __forceinline__ unsigned short f2bf(float f) {  // f32->bf16 RN
  unsigned int u = __float_as_uint(f);
  u += 0x7FFFu + ((u >> 16) & 1u);
  return (unsigned short)(u >> 16);
}
__device__ __forceinline__ float bf2f(unsigned short u) {
  return __uint_as_float(((unsigned int)u) << 16);
}

// ---------------- Kernel 1: forward Haar along W, transposed bf16 store -----
__global__ __launch_bounds__(256) void k_fwdW(const float* __restrict__ x,
                                              unsigned short* __restrict__ xt) {
  __shared__ float tile[32][257];  // 32 rows (h) x 256 cols (w), pitch 257
  const int blk = blockIdx.x;      // img*8 + htile
  const int img = blk >> 3;        // b*64 + c
  const int h0 = (blk & 7) << 5;
  const int tid = threadIdx.x;

  const float* __restrict__ src = x + ((size_t)img << 16) + ((size_t)h0 << 8);
#pragma unroll
  for (int j = 0; j < 32; ++j) tile[j][tid] = src[(j << 8) + tid];
  __syncthreads();

#pragma unroll
  for (int ls = 1; ls <= 8; ++ls) {
    const int s = 1 << ls;
    const int hs = s >> 1;
    const int ppr = 256 >> ls;
    const int total = 32 * ppr;
    for (int idx = tid; idx < total; idx += 256) {
      const int r = idx / ppr;
      const int i = idx - r * ppr;
      float* row = &tile[r][0];
      const int p0 = i * s;
      const float e = row[p0];
      const float o = row[p0 + hs];
      row[p0] = kNorm * (e + o);
      row[p0 + hs] = kNorm * (e - o);
    }
    __syncthreads();
  }

  // transposed bf16 write with in-place -> subband permutation: xt[img][wref][h]
  const int g8 = tid >> 5;
  const int l = tid & 31;
  unsigned short* __restrict__ dst = xt + ((size_t)img << 16) + h0;
#pragma unroll
  for (int k = 0; k < 32; ++k) {
    const int wp = g8 + (k << 3);
    const int wr = ip2ref(wp);
    dst[((size_t)wr << 8) + l] = f2bf(tile[l][wp]);
  }
}

// ---------------- Kernel 2: Hh fwd + MFMA mix + Hh inv (in-place, bf16 ws) --
// LDS rotation swizzle: addr(c,h) = c*256 + ((h+c)&255)  (f32 elements)
__device__ __forceinline__ int swz(int c, int h) {
  return (c << 8) | ((h + c) & 255);
}

__global__ __launch_bounds__(256, 2) void k_mid(unsigned short* __restrict__ ws,
                                                const float* __restrict__ vv,
                                                const float* __restrict__ cw,
                                                const float* __restrict__ tt) {
  __shared__ float tile[16384];  // 64 KiB: 64 channels x 256 h, swizzled
  const int blk = blockIdx.x;    // b*256 + w
  const int b = blk >> 8;
  const int w = blk & 255;
  const int tid = threadIdx.x;

  unsigned short* __restrict__ base = ws + ((size_t)b << 22) + ((size_t)w << 8);

  // ---- slab load: 512B contiguous per 32 lanes, bf16 -> f32 tile ----
  const int hc = (tid & 31) << 3;  // h chunk start
  const int cb = tid >> 5;         // 0..7
#pragma unroll
  for (int k = 0; k < 8; ++k) {
    const int c = cb + (k << 3);
    const ushort8 raw =
        *reinterpret_cast<const ushort8*>(base + ((size_t)c << 16) + hc);
#pragma unroll
    for (int j = 0; j < 8; ++j) tile[swz(c, hc + j)] = bf2f(raw[j]);
  }
  __syncthreads();

  // ---- forward Haar along h: two levels per barrier (quad lifting) ----
#pragma unroll
  for (int ls = 1; ls <= 7; ls += 2) {
    const int s = 1 << ls;
    const int hs = s >> 1;
    const int s2 = s << 1;
    const int total = (128 >> ls) << 6;
    for (int idx = tid; idx < total; idx += 256) {
      const int c = idx & 63;
      const int q = idx >> 6;
      const int p0 = q * s2;
      const float e0 = tile[swz(c, p0)];
      const float o0 = tile[swz(c, p0 + hs)];
      const float e1 = tile[swz(c, p0 + s)];
      const float o1 = tile[swz(c, p0 + s + hs)];
      const float a0 = kNorm * (e0 + o0);
      const float d0 = kNorm * (e0 - o0);
      const float a1 = kNorm * (e1 + o1);
      const float d1 = kNorm * (e1 - o1);
      tile[swz(c, p0)]          = kNorm * (a0 + a1);
      tile[swz(c, p0 + s)]      = kNorm * (a0 - a1);
      tile[swz(c, p0 + hs)]     = d0;
      tile[swz(c, p0 + s + hs)] = d1;
    }
    __syncthreads();
  }

  // ---- A-fragment preload (per wave: 64-row h strip, K=64 channels) ----
  // mfma_f32_16x16x32_bf16: A[m][k]: m=lane&15, k=8*(lane>>4)+j
  const int strip = (tid >> 6) << 6;  // wave id * 64
  const int l15 = tid & 15;
  const int l4 = (tid & 63) >> 4;
  short8 afr[2][4];
#pragma unroll
  for (int kt = 0; kt < 2; ++kt)
#pragma unroll
    for (int mt = 0; mt < 4; ++mt) {
      const int hh = strip + (mt << 4) + l15;
      const int c0 = (kt << 5) + (l4 << 3);
      short8 a;
#pragma unroll
      for (int j = 0; j < 8; ++j) a[j] = (short)f2bf(tile[swz(c0 + j, hh)]);
      afr[kt][mt] = a;
    }
  __syncthreads();  // A reads done before epilogue writes into tile

  // ---- GEMM: D[h, o'] = F[h,c] * Wc[c,o'],  o' = p*64+o, N=128, K=64 ----
  // B[k][n]: n=lane&15 (o'), k=8*(lane>>4)+j (c); loaded from global (L1/L2)
  f32x4 acc[4][8];
#pragma unroll
  for (int mt = 0; mt < 4; ++mt)
#pragma unroll
    for (int nt = 0; nt < 8; ++nt) {
      f32x4 z = {0.f, 0.f, 0.f, 0.f};
      acc[mt][nt] = z;
    }
#pragma unroll
  for (int nt = 0; nt < 8; ++nt) {
    const int op = (nt << 4) + l15;  // o' in [0,128)
    const int p = op >> 6;
    const int o = op & 63;
    const int cA = l4 << 3;
    const float* __restrict__ wrow = cw + (p << 12) + (o << 6);
    const float4 wa = *reinterpret_cast<const float4*>(wrow + cA);
    const float4 wb = *reinterpret_cast<const float4*>(wrow + cA + 4);
    const float4 wc = *reinterpret_cast<const float4*>(wrow + 32 + cA);
    const float4 wd = *reinterpret_cast<const float4*>(wrow + 32 + cA + 4);
    short8 b0, b1;
    b0[0] = (short)f2bf(wa.x); b0[1] = (short)f2bf(wa.y);
    b0[2] = (short)f2bf(wa.z); b0[3] = (short)f2bf(wa.w);
    b0[4] = (short)f2bf(wb.x); b0[5] = (short)f2bf(wb.y);
    b0[6] = (short)f2bf(wb.z); b0[7] = (short)f2bf(wb.w);
    b1[0] = (short)f2bf(wc.x); b1[1] = (short)f2bf(wc.y);
    b1[2] = (short)f2bf(wc.z); b1[3] = (short)f2bf(wc.w);
    b1[4] = (short)f2bf(wd.x); b1[5] = (short)f2bf(wd.y);
    b1[6] = (short)f2bf(wd.z); b1[7] = (short)f2bf(wd.w);
#pragma unroll
    for (int mt = 0; mt < 4; ++mt)
      acc[mt][nt] = __builtin_amdgcn_mfma_f32_16x16x32_bf16(
          afr[0][mt], b0, acc[mt][nt], 0, 0, 0);
#pragma unroll
    for (int mt = 0; mt < 4; ++mt)
      acc[mt][nt] = __builtin_amdgcn_mfma_f32_16x16x32_bf16(
          afr[1][mt], b1, acc[mt][nt], 0, 0, 0);
  }

  // ---- epilogue: r[h,o] = softthr(v0[h]*D[h,o], t0[h]) + softthr(v1[h]*D[h,o+64], t1[h])
  // D lane map: col o' = lane&15, row h = strip + mt*16 + 4*(lane>>4) + reg
#pragma unroll
  for (int mt = 0; mt < 4; ++mt) {
    float v0r[4], v1r[4], t0r[4], t1r[4];
#pragma unroll
    for (int r = 0; r < 4; ++r) {
      const int hh = strip + (mt << 4) + (l4 << 2) + r;
      const int off = (ip2ref(hh) << 8) + w;
      v0r[r] = vv[off];
      v1r[r] = vv[65536 + off];
      t0r[r] = tt[off];
      t1r[r] = tt[65536 + off];
    }
#pragma unroll
    for (int ntL = 0; ntL < 4; ++ntL) {
      const int o = (ntL << 4) + l15;
      const f32x4 lo = acc[mt][ntL];
      const f32x4 hi = acc[mt][ntL + 4];
#pragma unroll
      for (int r = 0; r < 4; ++r) {
        const float g0 = lo[r] * v0r[r];
        const float g1 = hi[r] * v1r[r];
        float rr = 0.f;
        const float q0 = fabsf(g0) - t0r[r];
        if (q0 > 0.f) rr += copysignf(q0, g0);
        const float q1 = fabsf(g1) - t1r[r];
        if (q1 > 0.f) rr += copysignf(q1, g1);
        const int hh = strip + (mt << 4) + (l4 << 2) + r;
        tile[swz(o, hh)] = rr;
      }
    }
  }
  __syncthreads();

  // ---- inverse Haar along h: two levels per barrier (quad lifting) ----
#pragma unroll
  for (int ls = 8; ls >= 2; ls -= 2) {
    const int s = 1 << ls;
    const int hs = s >> 1;
    const int hq = hs >> 1;
    const int total = (256 >> ls) << 6;
    for (int idx = tid; idx < total; idx += 256) {
      const int c = idx & 63;
      const int q = idx >> 6;
      const int p0 = q * s;
      const float a = tile[swz(c, p0)];
      const float d = tile[swz(c, p0 + hs)];
      const float u0 = kNorm * (a + d);
      const float u1 = kNorm * (a - d);
      const float d0 = tile[swz(c, p0 + hq)];
      const float d1 = tile[swz(c, p0 + hs + hq)];
      tile[swz(c, p0)]           = kNorm * (u0 + d0);
      tile[swz(c, p0 + hq)]      = kNorm * (u0 - d0);
      tile[swz(c, p0 + hs)]      = kNorm * (u1 + d1);
      tile[swz(c, p0 + hs + hq)] = kNorm * (u1 - d1);
    }
    __syncthreads();
  }

  // ---- store slab back as bf16 (mirror of load; block footprint private) ---
#pragma unroll
  for (int k = 0; k < 8; ++k) {
    const int c = cb + (k << 3);
    ushort8 raw;
#pragma unroll
    for (int j = 0; j < 8; ++j) raw[j] = f2bf(tile[swz(c, hc + j)]);
    *reinterpret_cast<ushort8*>(base + ((size_t)c << 16) + hc) = raw;
  }
}

// ---------------- Kernel 3: inverse Haar along W + residual add -------------
__global__ __launch_bounds__(256) void k_invW(const unsigned short* __restrict__ at,
                                              const float* __restrict__ x,
                                              float* __restrict__ y) {
  __shared__ float tile[256][33];  // 256 w (in-place order) x 32 h, pitch 33
  const int blk = blockIdx.x;      // img*8 + htile
  const int img = blk >> 3;
  const int h0 = (blk & 7) << 5;
  const int tid = threadIdx.x;
  const int g8 = tid >> 5;
  const int l = tid & 31;

  const unsigned short* __restrict__ base = at + ((size_t)img << 16) + h0;
#pragma unroll
  for (int k = 0; k < 32; ++k) {
    const int wr = (g8 << 5) + k;
    const int wp = ref2ip(wr);
    tile[wp][l] = bf2f(base[((size_t)wr << 8) + l]);
  }
  __syncthreads();

#pragma unroll
  for (int ls = 8; ls >= 1; --ls) {
    const int s = 1 << ls;
    const int hs = s >> 1;
    const int ppc = 256 >> ls;
    const int total = 32 * ppc;
    for (int idx = tid; idx < total; idx += 256) {
      const int hcq = idx & 31;
      const int i = idx >> 5;
      const int p0 = i * s;
      const float a = tile[p0][hcq];
      const float d = tile[p0 + hs][hcq];
      tile[p0][hcq] = kNorm * (a + d);
      tile[p0 + hs][hcq] = kNorm * (a - d);
    }
    __syncthreads();
  }

  const float* __restrict__ xs = x + ((size_t)img << 16) + ((size_t)h0 << 8);
  float* __restrict__ yd = y + ((size_t)img << 16) + ((size_t)h0 << 8);
#pragma unroll
  for (int j = 0; j < 32; ++j) {
    yd[(j << 8) + tid] = tile[tid][j] + xs[(j << 8) + tid];
  }
}

}  // namespace

extern "C" void kernel_launch(void* const* d_in, const int* in_sizes, int n_in,
                              void* d_out, int out_size, void* d_ws, size_t ws_size,
                              hipStream_t stream) {
  (void)in_sizes; (void)n_in; (void)out_size; (void)ws_size;
  const float* x  = (const float*)d_in[0];
  const float* vv = (const float*)d_in[1];
  const float* cw = (const float*)d_in[2];
  const float* tt = (const float*)d_in[3];
  float* y = (float*)d_out;
  unsigned short* ws = (unsigned short*)d_ws;  // 128 MiB bf16 workspace

  k_fwdW<<<8192, 256, 0, stream>>>(x, ws);
  k_mid <<<4096, 256, 0, stream>>>(ws, vv, cw, tt);
  k_invW<<<8192, 256, 0, stream>>>(ws, x, y);
}